// Round 12
// baseline (392.318 us; speedup 1.0000x reference)
//
#include <hip/hip_runtime.h>

#define N_ 200000
#define E_ 6400000
#define F_ 128
#define H_ 16
#define C_ 10
#define B_ 512

#define CSH   14                     // src chunk: 16384 rows = 1 MB of P (L2-resident)
#define NCH   13                     // ceil(200000/16384)
#define SBSH  12                     // dst superbucket: 4096 nodes
#define NSB   49                     // ceil(200000/4096)
#define NKEY  (NCH * NSB)            // 637
#define NT    800                    // partition tiles
#define EPT   8000                   // NT*EPT == E_
#define N1    (N_ + 1)
#define STG2  11520                  // part2 staging cap (partition mean 10047, sigma ~100)
#define AGGB  782                    // ceil(N_/256): 4 nodes per thread-group

// ---------- 1. per-tile chunk histogram (src only) ----------
__global__ __launch_bounds__(256) void k_count0(const int* __restrict__ row, int* __restrict__ cnt0) {
    __shared__ int hist[NCH];
    int tid = threadIdx.x, tile = blockIdx.x;
    if (tid < NCH) hist[tid] = 0;
    __syncthreads();
    const int* r = row + (size_t)tile * EPT;
    for (int i = tid; i < EPT; i += 256) atomicAdd(&hist[r[i] >> CSH], 1);
    __syncthreads();
    if (tid < NCH) cnt0[(size_t)tid * NT + tile] = hist[tid];
}

// ---------- generic: per-key scan over NT tiles (4/thread), in place + totals ----------
__global__ __launch_bounds__(256) void k_scan_col(int* __restrict__ cnt_mat, int* __restrict__ keyTotal) {
    __shared__ int s[256];
    int k = blockIdx.x, t = threadIdx.x;
    int v[4];
    int seg = 0;
#pragma unroll
    for (int j = 0; j < 4; ++j) {
        int idx = 4 * t + j;
        v[j] = (idx < NT) ? cnt_mat[(size_t)k * NT + idx] : 0;
        seg += v[j];
    }
    s[t] = seg;
    __syncthreads();
    for (int off = 1; off < 256; off <<= 1) {
        int tmp = (t >= off) ? s[t - off] : 0;
        __syncthreads();
        s[t] += tmp;
        __syncthreads();
    }
    if (t == 255) keyTotal[k] = s[255];
    int running = s[t] - seg;
#pragma unroll
    for (int j = 0; j < 4; ++j) {
        int idx = 4 * t + j;
        if (idx < NT) {
            int old = v[j];
            cnt_mat[(size_t)k * NT + idx] = running;
            running += old;
        }
    }
}

// ---------- generic: scan n totals (n<=1024) -> start[n+1] ----------
__global__ __launch_bounds__(1024) void k_scan_top(const int* __restrict__ keyTotal, int* __restrict__ keyStart, int n) {
    __shared__ int s[1024];
    int t = threadIdx.x;
    int v = (t < n) ? keyTotal[t] : 0;
    s[t] = v;
    __syncthreads();
    for (int off = 1; off < 1024; off <<= 1) {
        int tmp = (t >= off) ? s[t - off] : 0;
        __syncthreads();
        s[t] += tmp;
        __syncthreads();
    }
    if (t < n) keyStart[t] = s[t] - v;
    if (t == n - 1) keyStart[n] = s[t];
}

// ---------- 2. part0: scatter by src chunk; word = dst<<14 | srcL ----------
__global__ __launch_bounds__(256) void k_part0(const int* __restrict__ row, const int* __restrict__ col,
                                               const int* __restrict__ cnt0, const int* __restrict__ chStart,
                                               unsigned int* __restrict__ edges0) {
    __shared__ int cur[NCH];
    int tid = threadIdx.x, tile = blockIdx.x;
    if (tid < NCH) cur[tid] = cnt0[(size_t)tid * NT + tile] + chStart[tid];
    __syncthreads();
    const int* r = row + (size_t)tile * EPT;
    const int* c = col + (size_t)tile * EPT;
    for (int i = tid; i < EPT; i += 256) {
        int src = r[i], dst = c[i];
        int p = atomicAdd(&cur[src >> CSH], 1);
        edges0[p] = ((unsigned int)dst << CSH) | (unsigned int)(src & ((1 << CSH) - 1));
    }
}

// ---------- 3. count1: histogram over (chunk, sb) keys; chunk from position ----------
__global__ __launch_bounds__(256) void k_count1(const unsigned int* __restrict__ edges0,
                                                const int* __restrict__ chStart, int* __restrict__ cnt1) {
    __shared__ int hist[NKEY];
    __shared__ int chS[NCH + 1];
    int tid = threadIdx.x, tile = blockIdx.x;
    for (int i = tid; i < NKEY; i += 256) hist[i] = 0;
    if (tid <= NCH) chS[tid] = chStart[tid];
    __syncthreads();
    int g = tile * EPT + tid;
    int lo = 0, hi = NCH;
    while (lo + 1 < hi) { int m = (lo + hi) >> 1; if (g >= chS[m]) lo = m; else hi = m; }
    int cc = lo;
    for (int i = tid; i < EPT; i += 256, g += 256) {
        while (g >= chS[cc + 1]) ++cc;
        unsigned int w = edges0[g];
        atomicAdd(&hist[cc * NSB + (w >> 26)], 1);       // w>>26 == dst>>12
    }
    __syncthreads();
    for (int i = tid; i < NKEY; i += 256) cnt1[(size_t)i * NT + tile] = hist[i];
}

// ---------- 4. part1: scatter by (chunk, sb); word = dstlocal<<14 | srcL ----------
__global__ __launch_bounds__(256) void k_part1(const unsigned int* __restrict__ edges0,
                                               const int* __restrict__ chStart, const int* __restrict__ cnt1,
                                               const int* __restrict__ ks1, unsigned int* __restrict__ edges1) {
    __shared__ int cur[NKEY];
    __shared__ int chS[NCH + 1];
    int tid = threadIdx.x, tile = blockIdx.x;
    for (int i = tid; i < NKEY; i += 256) cur[i] = cnt1[(size_t)i * NT + tile] + ks1[i];
    if (tid <= NCH) chS[tid] = chStart[tid];
    __syncthreads();
    int g = tile * EPT + tid;
    int lo = 0, hi = NCH;
    while (lo + 1 < hi) { int m = (lo + hi) >> 1; if (g >= chS[m]) lo = m; else hi = m; }
    int cc = lo;
    for (int i = tid; i < EPT; i += 256, g += 256) {
        while (g >= chS[cc + 1]) ++cc;
        unsigned int w = edges0[g];
        int key = cc * NSB + (w >> 26);
        int p = atomicAdd(&cur[key], 1);
        edges1[p] = (((w >> CSH) & 4095u) << CSH) | (w & 16383u);
    }
}

// ---------- 5. part2: per-(c,sb) 12-bit LDS counting sort by dst; writes off16 (+sentinel), final src ----------
__global__ __launch_bounds__(256) void k_part2(unsigned int* __restrict__ edges1, const int* __restrict__ ks1,
                                               unsigned short* __restrict__ off16, unsigned int* __restrict__ spill) {
    __shared__ unsigned int stg[STG2];   // 45 KB
    __shared__ int cnt[4096];            // 16 KB
    __shared__ int aux[256];             // 1 KB
    int b = blockIdx.x, tid = threadIdx.x;
    int c = b / NSB, sb = b % NSB;
    int s = ks1[b], e = ks1[b + 1], len = e - s;
    // fused sentinel: total length of the last superbucket's partition
    if (sb == NSB - 1 && tid == 0) off16[(size_t)c * N1 + N_] = (unsigned short)len;
    for (int i = tid; i < 4096; i += 256) cnt[i] = 0;
    __syncthreads();
    bool small = (len <= STG2);
    if (small) {
        for (int i = tid; i < len; i += 256) {
            unsigned int w = edges1[s + i];
            stg[i] = w;
            atomicAdd(&cnt[w >> CSH], 1);
        }
    } else {   // statistically unreachable; correct fallback via spill (edges0 region, dead here)
        for (int i = tid; i < len; i += 256) {
            unsigned int w = edges1[s + i];
            spill[s + i] = w;
            atomicAdd(&cnt[w >> CSH], 1);
        }
    }
    __syncthreads();
    // exclusive scan of cnt[4096]: 16 per thread + block scan
    int base = tid * 16;
    int vals[16];
    int run = 0;
#pragma unroll
    for (int j = 0; j < 16; ++j) { vals[j] = cnt[base + j]; run += vals[j]; }
    aux[tid] = run;
    __syncthreads();
    for (int o = 1; o < 256; o <<= 1) {
        int tmp = (tid >= o) ? aux[tid - o] : 0;
        __syncthreads();
        aux[tid] += tmp;
        __syncthreads();
    }
    int acc = aux[tid] - run;              // exclusive base for this thread's 16 keys
    int nb = (sb << SBSH) + base;
#pragma unroll
    for (int j = 0; j < 16; ++j) {
        int v = vals[j];
        cnt[base + j] = acc;               // becomes running cursor
        int n = nb + j;
        if (n < N_) off16[(size_t)c * N1 + n] = (unsigned short)acc;
        acc += v;
    }
    __syncthreads();
    if (small) {
        for (int i = tid; i < len; i += 256) {
            unsigned int w = stg[i];
            int pos = atomicAdd(&cnt[w >> CSH], 1);
            edges1[s + pos] = ((unsigned int)c << CSH) | (w & 16383u);
        }
    } else {
        for (int i = tid; i < len; i += 256) {
            unsigned int w = spill[s + i];
            int pos = atomicAdd(&cnt[w >> CSH], 1);
            edges1[s + pos] = ((unsigned int)c << CSH) | (w & 16383u);
        }
    }
}

// ---------- 8. GEMM1 (+fused dis): dis[n]=rsqrt(1+deg from off16); P = dis*(x@W1) ----------
__global__ __launch_bounds__(256) void k_gemm1s(const float* __restrict__ x, const float* __restrict__ W1,
                                                const unsigned short* __restrict__ off16, const int* __restrict__ ks1g,
                                                float* __restrict__ dis, float* __restrict__ P) {
    __shared__ float w[F_ * H_];
    __shared__ int ks[NKEY + 1];
    for (int i = threadIdx.x; i < F_ * H_; i += 256) w[i] = W1[i];
    for (int i = threadIdx.x; i <= NKEY; i += 256) ks[i] = ks1g[i];
    __syncthreads();
    int n = blockIdx.x * 256 + threadIdx.x;
    if (n >= N_) return;
    int sb = n >> SBSH, sb1 = (n + 1) >> SBSH;
    int deg = 0;
#pragma unroll
    for (int c = 0; c < NCH; ++c) {
        int s = ks[c * NSB + sb]  + off16[(size_t)c * N1 + n];
        int e = ks[c * NSB + sb1] + off16[(size_t)c * N1 + n + 1];
        deg += e - s;
    }
    float dn = rsqrtf(1.0f + (float)deg);
    dis[n] = dn;
    float acc[H_];
#pragma unroll
    for (int h = 0; h < H_; ++h) acc[h] = 0.f;
    const float4* xr = reinterpret_cast<const float4*>(x + (size_t)n * F_);
#pragma unroll 4
    for (int k4 = 0; k4 < F_ / 4; ++k4) {
        float4 xv = xr[k4];
        int k = k4 * 4;
#pragma unroll
        for (int h = 0; h < H_; ++h) {
            acc[h] += xv.x * w[(k + 0) * H_ + h] + xv.y * w[(k + 1) * H_ + h]
                    + xv.z * w[(k + 2) * H_ + h] + xv.w * w[(k + 3) * H_ + h];
        }
    }
    float* o = P + (size_t)n * H_;
#pragma unroll
    for (int h = 0; h < H_; h += 4)
        *(float4*)(o + h) = make_float4(acc[h] * dn, acc[h + 1] * dn, acc[h + 2] * dn, acc[h + 3] * dn);
}

// ---------- 10. GEMM2: P = dis*(hin@W2)  (hin already ReLU'd by agg<1>) ----------
__global__ __launch_bounds__(256) void k_gemm2s(const float* __restrict__ hin, const float* __restrict__ W2,
                                                const float* __restrict__ dis, float* __restrict__ P) {
    __shared__ float w[H_ * H_];
    if (threadIdx.x < H_ * H_) w[threadIdx.x] = W2[threadIdx.x];
    __syncthreads();
    int n = blockIdx.x * 256 + threadIdx.x;
    if (n >= N_) return;
    float hv[H_];
    const float4* hr = reinterpret_cast<const float4*>(hin + (size_t)n * H_);
#pragma unroll
    for (int q = 0; q < 4; ++q) {
        float4 v = hr[q];
        hv[q * 4 + 0] = v.x; hv[q * 4 + 1] = v.y; hv[q * 4 + 2] = v.z; hv[q * 4 + 3] = v.w;
    }
    float acc[H_];
#pragma unroll
    for (int h = 0; h < H_; ++h) acc[h] = 0.f;
#pragma unroll
    for (int k = 0; k < H_; ++k)
#pragma unroll
        for (int h = 0; h < H_; ++h) acc[h] += hv[k] * w[k * H_ + h];
    float dn = dis[n];
    float* o = P + (size_t)n * H_;
#pragma unroll
    for (int h = 0; h < H_; h += 4)
        *(float4*)(o + h) = make_float4(acc[h] * dn, acc[h + 1] * dn, acc[h + 2] * dn, acc[h + 3] * dn);
}

// ---------- 9/11. CSR aggregation: 4 adjacent nodes per thread, flat per-chunk range ----------
// thread = (node-group of 4, hq); within partition (c,sb) the 4 nodes' sublists are
// CONTIGUOUS -> one flat loop [s0,e3) with independent iterations (deep MLP);
// segment membership resolved branchlessly with 3 compares + mask-FMAs.
// Invariants kept from R8/R11: wave walks one chunk window at a time in order;
// 4 hq-lanes cover each 64B P-line; csr read order/footprint unchanged.
template <int RELU>
__global__ __launch_bounds__(256) void k_agg(const float4* __restrict__ P4, const unsigned int* __restrict__ csr,
                                             const unsigned short* __restrict__ off16, const int* __restrict__ ks1g,
                                             const float* __restrict__ dis, const float* __restrict__ bias,
                                             float4* __restrict__ Q4) {
    __shared__ int ks[NKEY + 1];
    for (int i = threadIdx.x; i <= NKEY; i += 256) ks[i] = ks1g[i];
    __syncthreads();
    int g = threadIdx.x >> 2, hq = threadIdx.x & 3;
    int n0 = blockIdx.x * 256 + g * 4;            // group of nodes n0..n0+3 (N_ % 4 == 0)
    if (n0 >= N_) return;
    int sb  = n0 >> SBSH;                          // group never straddles sb (4 | 4096)
    int sbE = (n0 + 4) >> SBSH;                    // for the group-end bound
    float4 acc0 = {0,0,0,0}, acc1 = {0,0,0,0}, acc2 = {0,0,0,0}, acc3 = {0,0,0,0};
    // pipelined bounds: load chunk-0 offsets
    const unsigned short* ob = off16 + n0;
    ushort4 o4 = *(const ushort4*)ob;
    unsigned short o5 = ob[4];
#pragma unroll
    for (int c = 0; c < NCH; ++c) {
        int bs = ks[c * NSB + sb];
        int be = ks[c * NSB + sbE];
        int s0 = bs + o4.x;
        int s1 = bs + o4.y;
        int s2 = bs + o4.z;
        int s3 = bs + o4.w;
        int e3 = be + o5;
        if (c + 1 < NCH) {                         // prefetch next chunk's offsets
            const unsigned short* obn = off16 + (size_t)(c + 1) * N1 + n0;
            o4 = *(const ushort4*)obn;
            o5 = obn[4];
        }
#pragma unroll 4
        for (int p = s0; p < e3; ++p) {
            float4 v = P4[(size_t)csr[p] * 4 + hq];
            float w0 = (p < s1) ? 1.f : 0.f;
            float w1 = (p >= s1 && p < s2) ? 1.f : 0.f;
            float w2 = (p >= s2 && p < s3) ? 1.f : 0.f;
            float w3 = (p >= s3) ? 1.f : 0.f;
            acc0.x += w0 * v.x; acc0.y += w0 * v.y; acc0.z += w0 * v.z; acc0.w += w0 * v.w;
            acc1.x += w1 * v.x; acc1.y += w1 * v.y; acc1.z += w1 * v.z; acc1.w += w1 * v.w;
            acc2.x += w2 * v.x; acc2.y += w2 * v.y; acc2.z += w2 * v.z; acc2.w += w2 * v.w;
            acc3.x += w3 * v.x; acc3.y += w3 * v.y; acc3.z += w3 * v.z; acc3.w += w3 * v.w;
        }
    }
    float4 d4 = *(const float4*)(dis + n0);
    float4 b4 = ((const float4*)bias)[hq];
#define FINISH(ACC, K, DN)                                            \
    {                                                                 \
        float4 self = P4[(size_t)(n0 + K) * 4 + hq];                  \
        float4 v;                                                     \
        v.x = (DN) * (ACC.x + self.x) + b4.x;                         \
        v.y = (DN) * (ACC.y + self.y) + b4.y;                         \
        v.z = (DN) * (ACC.z + self.z) + b4.z;                         \
        v.w = (DN) * (ACC.w + self.w) + b4.w;                         \
        if (RELU) {                                                   \
            v.x = fmaxf(v.x, 0.f); v.y = fmaxf(v.y, 0.f);             \
            v.z = fmaxf(v.z, 0.f); v.w = fmaxf(v.w, 0.f);             \
        }                                                             \
        Q4[(size_t)(n0 + K) * 4 + hq] = v;                            \
    }
    FINISH(acc0, 0, d4.x)
    FINISH(acc1, 1, d4.y)
    FINISH(acc2, 2, d4.z)
    FINISH(acc3, 3, d4.w)
#undef FINISH
}

// ---------- 12. pool + fc ----------
__global__ __launch_bounds__(256) void k_pool_fc(const float* __restrict__ h2, const int* __restrict__ batch,
                                                 const float* __restrict__ Wfc, const float* __restrict__ bfc,
                                                 float* __restrict__ out) {
    int b = blockIdx.x;
    int lo = 0, hi = N_;
    while (lo < hi) { int m = (lo + hi) >> 1; if (batch[m] < b) lo = m + 1; else hi = m; }
    int start = lo;
    lo = start; hi = N_;
    while (lo < hi) { int m = (lo + hi) >> 1; if (batch[m] < b + 1) lo = m + 1; else hi = m; }
    int end = lo;

    int t = threadIdx.x;
    int h = t & 15, q = t >> 4;
    float acc = 0.f;
    for (int n = start + q; n < end; n += 16) acc += h2[(size_t)n * H_ + h];
    acc += __shfl_xor(acc, 16);
    acc += __shfl_xor(acc, 32);

    __shared__ float part[4][H_];
    __shared__ float pooled[H_];
    if ((t & 63) < 16) part[t >> 6][h] = acc;
    __syncthreads();
    if (t < H_) {
        float s2 = part[0][t] + part[1][t] + part[2][t] + part[3][t];
        pooled[t] = s2 / fmaxf((float)(end - start), 1.0f);
    }
    __syncthreads();
    if (t < C_) {
        float o = bfc[t];
#pragma unroll
        for (int hh = 0; hh < H_; ++hh) o += pooled[hh] * Wfc[hh * C_ + t];
        out[b * C_ + t] = o;
    }
}

extern "C" void kernel_launch(void* const* d_in, const int* in_sizes, int n_in,
                              void* d_out, int out_size, void* d_ws, size_t ws_size,
                              hipStream_t stream) {
    const float* x    = (const float*)d_in[0];
    const int*   ei   = (const int*)d_in[1];
    const int*   batch= (const int*)d_in[2];
    const float* W1   = (const float*)d_in[3];
    const float* b1   = (const float*)d_in[4];
    const float* W2   = (const float*)d_in[5];
    const float* b2   = (const float*)d_in[6];
    const float* Wfc  = (const float*)d_in[7];
    const float* bfc  = (const float*)d_in[8];
    float* out = (float*)d_out;

    const int* row = ei;          // sources
    const int* col = ei + E_;     // destinations

    size_t off = 0;
    auto alloc = [&](size_t bytes) -> void* {
        void* p = (char*)d_ws + off;
        off += (bytes + 255) & ~(size_t)255;
        return p;
    };
    int*            cnt0     = (int*)alloc((size_t)NCH * NT * 4);        // 41.6 KB
    int*            chTotal  = (int*)alloc((size_t)NCH * 4);
    int*            chStart  = (int*)alloc((size_t)(NCH + 1) * 4);
    // union: cnt1 (637*800*4 = 2.04 MB) dead after k_part1; off16 (13*N1*2 = 5.2 MB) written in k_part2
    char*           U        = (char*)alloc((size_t)NCH * N1 * 2);
    int*            cnt1     = (int*)U;
    unsigned short* off16    = (unsigned short*)U;
    int*            keyTotal = (int*)alloc((size_t)NKEY * 4);
    int*            ks1      = (int*)alloc((size_t)(NKEY + 1) * 4);
    unsigned int*   edges1   = (unsigned int*)alloc((size_t)E_ * 4);     // 25.6 MB
    float*          dis      = (float*)alloc((size_t)N_ * 4);            // 0.8 MB
    float*          P        = (float*)alloc((size_t)N_ * H_ * 4);       // 12.8 MB
    float*          Q        = (float*)alloc((size_t)N_ * H_ * 4);       // 12.8 MB, contiguous after P
    // edges0 (E_ words = 25.6 MB) aliases P∪Q: consumed by part1, before gemm1 writes P.
    unsigned int*   edges0   = (unsigned int*)P;
    unsigned int*   spill    = (unsigned int*)P;                         // part2 fallback; edges0 dead by then
    (void)ws_size; (void)in_sizes; (void)n_in; (void)out_size;

    const int gridN = (N_ + 255) / 256;

    // stage 0: partition by src chunk (13 bins)
    k_count0  <<<NT, 256, 0, stream>>>(row, cnt0);
    k_scan_col<<<NCH, 256, 0, stream>>>(cnt0, chTotal);
    k_scan_top<<<1, 1024, 0, stream>>>(chTotal, chStart, NCH);
    k_part0   <<<NT, 256, 0, stream>>>(row, col, cnt0, chStart, edges0);
    // stage 1: partition by (chunk, dst>>12) (637 bins)
    k_count1  <<<NT, 256, 0, stream>>>(edges0, chStart, cnt1);
    k_scan_col<<<NKEY, 256, 0, stream>>>(cnt1, keyTotal);
    k_scan_top<<<1, 1024, 0, stream>>>(keyTotal, ks1, NKEY);
    k_part1   <<<NT, 256, 0, stream>>>(edges0, chStart, cnt1, ks1, edges1);
    // stage 2: in-partition 12-bit sort by dst -> per-chunk CSR (off16 + sentinel) + final src edges
    k_part2   <<<NKEY, 256, 0, stream>>>(edges1, ks1, off16, spill);

    // conv1 (dis fused into gemm1)
    k_gemm1s<<<gridN, 256, 0, stream>>>(x, W1, off16, ks1, dis, P);
    k_agg<1><<<AGGB, 256, 0, stream>>>((const float4*)P, edges1, off16, ks1, dis, b1, (float4*)Q);
    // conv2
    k_gemm2s<<<gridN, 256, 0, stream>>>(Q, W2, dis, P);
    k_agg<0><<<AGGB, 256, 0, stream>>>((const float4*)P, edges1, off16, ks1, dis, b2, (float4*)Q);

    k_pool_fc<<<B_, 256, 0, stream>>>(Q, batch, Wfc, bfc, out);
}

// Round 13
// 345.958 us; speedup vs baseline: 1.1340x; 1.1340x over previous
//
#include <hip/hip_runtime.h>

#define N_ 200000
#define E_ 6400000
#define F_ 128
#define H_ 16
#define C_ 10
#define B_ 512

#define CSH   14                     // src chunk: 16384 rows = 1 MB of P (L2-resident)
#define NCH   13                     // ceil(200000/16384)
#define SBSH  12                     // dst superbucket: 4096 nodes
#define NSB   49                     // ceil(200000/4096)
#define NKEY  (NCH * NSB)            // 637
#define NT    800                    // partition tiles
#define EPT   8000                   // NT*EPT == E_
#define N1    (N_ + 1)
#define STG2  11520                  // part2 staging cap (partition mean 10047, sigma ~100)
#define AGGB  1563                   // ceil(N_*2/256): 2 nodes per thread

// ---------- 1. per-tile chunk histogram (src only) ----------
__global__ __launch_bounds__(256) void k_count0(const int* __restrict__ row, int* __restrict__ cnt0) {
    __shared__ int hist[NCH];
    int tid = threadIdx.x, tile = blockIdx.x;
    if (tid < NCH) hist[tid] = 0;
    __syncthreads();
    const int* r = row + (size_t)tile * EPT;
    for (int i = tid; i < EPT; i += 256) atomicAdd(&hist[r[i] >> CSH], 1);
    __syncthreads();
    if (tid < NCH) cnt0[(size_t)tid * NT + tile] = hist[tid];
}

// ---------- generic: per-key scan over NT tiles (4/thread), in place + totals ----------
__global__ __launch_bounds__(256) void k_scan_col(int* __restrict__ cnt_mat, int* __restrict__ keyTotal) {
    __shared__ int s[256];
    int k = blockIdx.x, t = threadIdx.x;
    int v[4];
    int seg = 0;
#pragma unroll
    for (int j = 0; j < 4; ++j) {
        int idx = 4 * t + j;
        v[j] = (idx < NT) ? cnt_mat[(size_t)k * NT + idx] : 0;
        seg += v[j];
    }
    s[t] = seg;
    __syncthreads();
    for (int off = 1; off < 256; off <<= 1) {
        int tmp = (t >= off) ? s[t - off] : 0;
        __syncthreads();
        s[t] += tmp;
        __syncthreads();
    }
    if (t == 255) keyTotal[k] = s[255];
    int running = s[t] - seg;
#pragma unroll
    for (int j = 0; j < 4; ++j) {
        int idx = 4 * t + j;
        if (idx < NT) {
            int old = v[j];
            cnt_mat[(size_t)k * NT + idx] = running;
            running += old;
        }
    }
}

// ---------- generic: scan n totals (n<=1024) -> start[n+1] ----------
__global__ __launch_bounds__(1024) void k_scan_top(const int* __restrict__ keyTotal, int* __restrict__ keyStart, int n) {
    __shared__ int s[1024];
    int t = threadIdx.x;
    int v = (t < n) ? keyTotal[t] : 0;
    s[t] = v;
    __syncthreads();
    for (int off = 1; off < 1024; off <<= 1) {
        int tmp = (t >= off) ? s[t - off] : 0;
        __syncthreads();
        s[t] += tmp;
        __syncthreads();
    }
    if (t < n) keyStart[t] = s[t] - v;
    if (t == n - 1) keyStart[n] = s[t];
}

// ---------- 2. part0: scatter by src chunk; word = dst<<14 | srcL ----------
__global__ __launch_bounds__(256) void k_part0(const int* __restrict__ row, const int* __restrict__ col,
                                               const int* __restrict__ cnt0, const int* __restrict__ chStart,
                                               unsigned int* __restrict__ edges0) {
    __shared__ int cur[NCH];
    int tid = threadIdx.x, tile = blockIdx.x;
    if (tid < NCH) cur[tid] = cnt0[(size_t)tid * NT + tile] + chStart[tid];
    __syncthreads();
    const int* r = row + (size_t)tile * EPT;
    const int* c = col + (size_t)tile * EPT;
    for (int i = tid; i < EPT; i += 256) {
        int src = r[i], dst = c[i];
        int p = atomicAdd(&cur[src >> CSH], 1);
        edges0[p] = ((unsigned int)dst << CSH) | (unsigned int)(src & ((1 << CSH) - 1));
    }
}

// ---------- 3. count1: histogram over (chunk, sb) keys; chunk from position ----------
__global__ __launch_bounds__(256) void k_count1(const unsigned int* __restrict__ edges0,
                                                const int* __restrict__ chStart, int* __restrict__ cnt1) {
    __shared__ int hist[NKEY];
    __shared__ int chS[NCH + 1];
    int tid = threadIdx.x, tile = blockIdx.x;
    for (int i = tid; i < NKEY; i += 256) hist[i] = 0;
    if (tid <= NCH) chS[tid] = chStart[tid];
    __syncthreads();
    int g = tile * EPT + tid;
    int lo = 0, hi = NCH;
    while (lo + 1 < hi) { int m = (lo + hi) >> 1; if (g >= chS[m]) lo = m; else hi = m; }
    int cc = lo;
    for (int i = tid; i < EPT; i += 256, g += 256) {
        while (g >= chS[cc + 1]) ++cc;
        unsigned int w = edges0[g];
        atomicAdd(&hist[cc * NSB + (w >> 26)], 1);       // w>>26 == dst>>12
    }
    __syncthreads();
    for (int i = tid; i < NKEY; i += 256) cnt1[(size_t)i * NT + tile] = hist[i];
}

// ---------- 4. part1: scatter by (chunk, sb); word = dstlocal<<14 | srcL ----------
__global__ __launch_bounds__(256) void k_part1(const unsigned int* __restrict__ edges0,
                                               const int* __restrict__ chStart, const int* __restrict__ cnt1,
                                               const int* __restrict__ ks1, unsigned int* __restrict__ edges1) {
    __shared__ int cur[NKEY];
    __shared__ int chS[NCH + 1];
    int tid = threadIdx.x, tile = blockIdx.x;
    for (int i = tid; i < NKEY; i += 256) cur[i] = cnt1[(size_t)i * NT + tile] + ks1[i];
    if (tid <= NCH) chS[tid] = chStart[tid];
    __syncthreads();
    int g = tile * EPT + tid;
    int lo = 0, hi = NCH;
    while (lo + 1 < hi) { int m = (lo + hi) >> 1; if (g >= chS[m]) lo = m; else hi = m; }
    int cc = lo;
    for (int i = tid; i < EPT; i += 256, g += 256) {
        while (g >= chS[cc + 1]) ++cc;
        unsigned int w = edges0[g];
        int key = cc * NSB + (w >> 26);
        int p = atomicAdd(&cur[key], 1);
        edges1[p] = (((w >> CSH) & 4095u) << CSH) | (w & 16383u);
    }
}

// ---------- 5. part2: per-(c,sb) 12-bit LDS counting sort by dst; writes off16 (+sentinel), final src ----------
__global__ __launch_bounds__(256) void k_part2(unsigned int* __restrict__ edges1, const int* __restrict__ ks1,
                                               unsigned short* __restrict__ off16, unsigned int* __restrict__ spill) {
    __shared__ unsigned int stg[STG2];   // 45 KB
    __shared__ int cnt[4096];            // 16 KB
    __shared__ int aux[256];             // 1 KB
    int b = blockIdx.x, tid = threadIdx.x;
    int c = b / NSB, sb = b % NSB;
    int s = ks1[b], e = ks1[b + 1], len = e - s;
    // fused sentinel: total length of the last superbucket's partition
    if (sb == NSB - 1 && tid == 0) off16[(size_t)c * N1 + N_] = (unsigned short)len;
    for (int i = tid; i < 4096; i += 256) cnt[i] = 0;
    __syncthreads();
    bool small = (len <= STG2);
    if (small) {
        for (int i = tid; i < len; i += 256) {
            unsigned int w = edges1[s + i];
            stg[i] = w;
            atomicAdd(&cnt[w >> CSH], 1);
        }
    } else {   // statistically unreachable; correct fallback via spill (edges0 region, dead here)
        for (int i = tid; i < len; i += 256) {
            unsigned int w = edges1[s + i];
            spill[s + i] = w;
            atomicAdd(&cnt[w >> CSH], 1);
        }
    }
    __syncthreads();
    // exclusive scan of cnt[4096]: 16 per thread + block scan
    int base = tid * 16;
    int vals[16];
    int run = 0;
#pragma unroll
    for (int j = 0; j < 16; ++j) { vals[j] = cnt[base + j]; run += vals[j]; }
    aux[tid] = run;
    __syncthreads();
    for (int o = 1; o < 256; o <<= 1) {
        int tmp = (tid >= o) ? aux[tid - o] : 0;
        __syncthreads();
        aux[tid] += tmp;
        __syncthreads();
    }
    int acc = aux[tid] - run;              // exclusive base for this thread's 16 keys
    int nb = (sb << SBSH) + base;
#pragma unroll
    for (int j = 0; j < 16; ++j) {
        int v = vals[j];
        cnt[base + j] = acc;               // becomes running cursor
        int n = nb + j;
        if (n < N_) off16[(size_t)c * N1 + n] = (unsigned short)acc;
        acc += v;
    }
    __syncthreads();
    if (small) {
        for (int i = tid; i < len; i += 256) {
            unsigned int w = stg[i];
            int pos = atomicAdd(&cnt[w >> CSH], 1);
            edges1[s + pos] = ((unsigned int)c << CSH) | (w & 16383u);
        }
    } else {
        for (int i = tid; i < len; i += 256) {
            unsigned int w = spill[s + i];
            int pos = atomicAdd(&cnt[w >> CSH], 1);
            edges1[s + pos] = ((unsigned int)c << CSH) | (w & 16383u);
        }
    }
}

// ---------- 8. GEMM1 (+fused dis): dis[n]=rsqrt(1+deg from off16); P = dis*(x@W1) ----------
__global__ __launch_bounds__(256) void k_gemm1s(const float* __restrict__ x, const float* __restrict__ W1,
                                                const unsigned short* __restrict__ off16, const int* __restrict__ ks1g,
                                                float* __restrict__ dis, float* __restrict__ P) {
    __shared__ float w[F_ * H_];
    __shared__ int ks[NKEY + 1];
    for (int i = threadIdx.x; i < F_ * H_; i += 256) w[i] = W1[i];
    for (int i = threadIdx.x; i <= NKEY; i += 256) ks[i] = ks1g[i];
    __syncthreads();
    int n = blockIdx.x * 256 + threadIdx.x;
    if (n >= N_) return;
    int sb = n >> SBSH, sb1 = (n + 1) >> SBSH;
    int deg = 0;
#pragma unroll
    for (int c = 0; c < NCH; ++c) {
        int s = ks[c * NSB + sb]  + off16[(size_t)c * N1 + n];
        int e = ks[c * NSB + sb1] + off16[(size_t)c * N1 + n + 1];
        deg += e - s;
    }
    float dn = rsqrtf(1.0f + (float)deg);
    dis[n] = dn;
    float acc[H_];
#pragma unroll
    for (int h = 0; h < H_; ++h) acc[h] = 0.f;
    const float4* xr = reinterpret_cast<const float4*>(x + (size_t)n * F_);
#pragma unroll 4
    for (int k4 = 0; k4 < F_ / 4; ++k4) {
        float4 xv = xr[k4];
        int k = k4 * 4;
#pragma unroll
        for (int h = 0; h < H_; ++h) {
            acc[h] += xv.x * w[(k + 0) * H_ + h] + xv.y * w[(k + 1) * H_ + h]
                    + xv.z * w[(k + 2) * H_ + h] + xv.w * w[(k + 3) * H_ + h];
        }
    }
    float* o = P + (size_t)n * H_;
#pragma unroll
    for (int h = 0; h < H_; h += 4)
        *(float4*)(o + h) = make_float4(acc[h] * dn, acc[h + 1] * dn, acc[h + 2] * dn, acc[h + 3] * dn);
}

// ---------- 10. GEMM2: P = dis*(hin@W2)  (hin already ReLU'd by agg<1>) ----------
__global__ __launch_bounds__(256) void k_gemm2s(const float* __restrict__ hin, const float* __restrict__ W2,
                                                const float* __restrict__ dis, float* __restrict__ P) {
    __shared__ float w[H_ * H_];
    if (threadIdx.x < H_ * H_) w[threadIdx.x] = W2[threadIdx.x];
    __syncthreads();
    int n = blockIdx.x * 256 + threadIdx.x;
    if (n >= N_) return;
    float hv[H_];
    const float4* hr = reinterpret_cast<const float4*>(hin + (size_t)n * H_);
#pragma unroll
    for (int q = 0; q < 4; ++q) {
        float4 v = hr[q];
        hv[q * 4 + 0] = v.x; hv[q * 4 + 1] = v.y; hv[q * 4 + 2] = v.z; hv[q * 4 + 3] = v.w;
    }
    float acc[H_];
#pragma unroll
    for (int h = 0; h < H_; ++h) acc[h] = 0.f;
#pragma unroll
    for (int k = 0; k < H_; ++k)
#pragma unroll
        for (int h = 0; h < H_; ++h) acc[h] += hv[k] * w[k * H_ + h];
    float dn = dis[n];
    float* o = P + (size_t)n * H_;
#pragma unroll
    for (int h = 0; h < H_; h += 4)
        *(float4*)(o + h) = make_float4(acc[h] * dn, acc[h + 1] * dn, acc[h + 2] * dn, acc[h + 3] * dn);
}

// ---------- 9/11. CSR aggregation: 2 adjacent nodes per thread, flat per-chunk range ----------
// thread = (node-pair, hq); within partition (c,sb) the pair's sublists are contiguous ->
// one flat loop [s0,e1) with independent iterations; membership = 1 compare.
// Invariants: wave walks one chunk window at a time in order; 4 hq-lanes per 64B line.
template <int RELU>
__global__ __launch_bounds__(256) void k_agg(const float4* __restrict__ P4, const unsigned int* __restrict__ csr,
                                             const unsigned short* __restrict__ off16, const int* __restrict__ ks1g,
                                             const float* __restrict__ dis, const float* __restrict__ bias,
                                             float4* __restrict__ Q4) {
    __shared__ int ks[NKEY + 1];
    for (int i = threadIdx.x; i <= NKEY; i += 256) ks[i] = ks1g[i];
    __syncthreads();
    int g = threadIdx.x >> 2, hq = threadIdx.x & 3;
    int n0 = blockIdx.x * 128 + g * 2;             // node pair n0, n0+1 (N_ even)
    if (n0 >= N_) return;
    int sb  = n0 >> SBSH;                          // pair never straddles sb (2 | 4096)
    int sbE = (n0 + 2) >> SBSH;                    // for the pair-end bound
    float4 acc0 = {0,0,0,0}, acc1 = {0,0,0,0};
    // pipelined bounds: chunk-0 offsets (n0 even -> ushort2 aligned)
    const unsigned short* ob = off16 + n0;
    ushort2 o2 = *(const ushort2*)ob;
    unsigned short oE = ob[2];
#pragma unroll
    for (int c = 0; c < NCH; ++c) {
        int bs = ks[c * NSB + sb];
        int be = ks[c * NSB + sbE];
        int s0 = bs + o2.x;
        int s1 = bs + o2.y;
        int e1 = be + oE;
        if (c + 1 < NCH) {                         // prefetch next chunk's offsets
            const unsigned short* obn = off16 + (size_t)(c + 1) * N1 + n0;
            o2 = *(const ushort2*)obn;
            oE = obn[2];
        }
#pragma unroll 4
        for (int p = s0; p < e1; ++p) {
            float4 v = P4[(size_t)csr[p] * 4 + hq];
            float w0 = (p < s1) ? 1.f : 0.f;
            float w1 = 1.f - w0;
            acc0.x += w0 * v.x; acc0.y += w0 * v.y; acc0.z += w0 * v.z; acc0.w += w0 * v.w;
            acc1.x += w1 * v.x; acc1.y += w1 * v.y; acc1.z += w1 * v.z; acc1.w += w1 * v.w;
        }
    }
    float2 d2 = *(const float2*)(dis + n0);
    float4 b4 = ((const float4*)bias)[hq];
#define FINISH(ACC, K, DN)                                            \
    {                                                                 \
        float4 self = P4[(size_t)(n0 + K) * 4 + hq];                  \
        float4 v;                                                     \
        v.x = (DN) * (ACC.x + self.x) + b4.x;                         \
        v.y = (DN) * (ACC.y + self.y) + b4.y;                         \
        v.z = (DN) * (ACC.z + self.z) + b4.z;                         \
        v.w = (DN) * (ACC.w + self.w) + b4.w;                         \
        if (RELU) {                                                   \
            v.x = fmaxf(v.x, 0.f); v.y = fmaxf(v.y, 0.f);             \
            v.z = fmaxf(v.z, 0.f); v.w = fmaxf(v.w, 0.f);             \
        }                                                             \
        Q4[(size_t)(n0 + K) * 4 + hq] = v;                            \
    }
    FINISH(acc0, 0, d2.x)
    FINISH(acc1, 1, d2.y)
#undef FINISH
}

// ---------- 12. pool + fc ----------
__global__ __launch_bounds__(256) void k_pool_fc(const float* __restrict__ h2, const int* __restrict__ batch,
                                                 const float* __restrict__ Wfc, const float* __restrict__ bfc,
                                                 float* __restrict__ out) {
    int b = blockIdx.x;
    int lo = 0, hi = N_;
    while (lo < hi) { int m = (lo + hi) >> 1; if (batch[m] < b) lo = m + 1; else hi = m; }
    int start = lo;
    lo = start; hi = N_;
    while (lo < hi) { int m = (lo + hi) >> 1; if (batch[m] < b + 1) lo = m + 1; else hi = m; }
    int end = lo;

    int t = threadIdx.x;
    int h = t & 15, q = t >> 4;
    float acc = 0.f;
    for (int n = start + q; n < end; n += 16) acc += h2[(size_t)n * H_ + h];
    acc += __shfl_xor(acc, 16);
    acc += __shfl_xor(acc, 32);

    __shared__ float part[4][H_];
    __shared__ float pooled[H_];
    if ((t & 63) < 16) part[t >> 6][h] = acc;
    __syncthreads();
    if (t < H_) {
        float s2 = part[0][t] + part[1][t] + part[2][t] + part[3][t];
        pooled[t] = s2 / fmaxf((float)(end - start), 1.0f);
    }
    __syncthreads();
    if (t < C_) {
        float o = bfc[t];
#pragma unroll
        for (int hh = 0; hh < H_; ++hh) o += pooled[hh] * Wfc[hh * C_ + t];
        out[b * C_ + t] = o;
    }
}

extern "C" void kernel_launch(void* const* d_in, const int* in_sizes, int n_in,
                              void* d_out, int out_size, void* d_ws, size_t ws_size,
                              hipStream_t stream) {
    const float* x    = (const float*)d_in[0];
    const int*   ei   = (const int*)d_in[1];
    const int*   batch= (const int*)d_in[2];
    const float* W1   = (const float*)d_in[3];
    const float* b1   = (const float*)d_in[4];
    const float* W2   = (const float*)d_in[5];
    const float* b2   = (const float*)d_in[6];
    const float* Wfc  = (const float*)d_in[7];
    const float* bfc  = (const float*)d_in[8];
    float* out = (float*)d_out;

    const int* row = ei;          // sources
    const int* col = ei + E_;     // destinations

    size_t off = 0;
    auto alloc = [&](size_t bytes) -> void* {
        void* p = (char*)d_ws + off;
        off += (bytes + 255) & ~(size_t)255;
        return p;
    };
    int*            cnt0     = (int*)alloc((size_t)NCH * NT * 4);        // 41.6 KB
    int*            chTotal  = (int*)alloc((size_t)NCH * 4);
    int*            chStart  = (int*)alloc((size_t)(NCH + 1) * 4);
    // union: cnt1 (637*800*4 = 2.04 MB) dead after k_part1; off16 (13*N1*2 = 5.2 MB) written in k_part2
    char*           U        = (char*)alloc((size_t)NCH * N1 * 2);
    int*            cnt1     = (int*)U;
    unsigned short* off16    = (unsigned short*)U;
    int*            keyTotal = (int*)alloc((size_t)NKEY * 4);
    int*            ks1      = (int*)alloc((size_t)(NKEY + 1) * 4);
    unsigned int*   edges1   = (unsigned int*)alloc((size_t)E_ * 4);     // 25.6 MB
    float*          dis      = (float*)alloc((size_t)N_ * 4);            // 0.8 MB
    float*          P        = (float*)alloc((size_t)N_ * H_ * 4);       // 12.8 MB
    float*          Q        = (float*)alloc((size_t)N_ * H_ * 4);       // 12.8 MB, contiguous after P
    // edges0 (E_ words = 25.6 MB) aliases P∪Q: consumed by part1, before gemm1 writes P.
    unsigned int*   edges0   = (unsigned int*)P;
    unsigned int*   spill    = (unsigned int*)P;                         // part2 fallback; edges0 dead by then
    (void)ws_size; (void)in_sizes; (void)n_in; (void)out_size;

    const int gridN = (N_ + 255) / 256;

    // stage 0: partition by src chunk (13 bins)
    k_count0  <<<NT, 256, 0, stream>>>(row, cnt0);
    k_scan_col<<<NCH, 256, 0, stream>>>(cnt0, chTotal);
    k_scan_top<<<1, 1024, 0, stream>>>(chTotal, chStart, NCH);
    k_part0   <<<NT, 256, 0, stream>>>(row, col, cnt0, chStart, edges0);
    // stage 1: partition by (chunk, dst>>12) (637 bins)
    k_count1  <<<NT, 256, 0, stream>>>(edges0, chStart, cnt1);
    k_scan_col<<<NKEY, 256, 0, stream>>>(cnt1, keyTotal);
    k_scan_top<<<1, 1024, 0, stream>>>(keyTotal, ks1, NKEY);
    k_part1   <<<NT, 256, 0, stream>>>(edges0, chStart, cnt1, ks1, edges1);
    // stage 2: in-partition 12-bit sort by dst -> per-chunk CSR (off16 + sentinel) + final src edges
    k_part2   <<<NKEY, 256, 0, stream>>>(edges1, ks1, off16, spill);

    // conv1 (dis fused into gemm1)
    k_gemm1s<<<gridN, 256, 0, stream>>>(x, W1, off16, ks1, dis, P);
    k_agg<1><<<AGGB, 256, 0, stream>>>((const float4*)P, edges1, off16, ks1, dis, b1, (float4*)Q);
    // conv2
    k_gemm2s<<<gridN, 256, 0, stream>>>(Q, W2, dis, P);
    k_agg<0><<<AGGB, 256, 0, stream>>>((const float4*)P, edges1, off16, ks1, dis, b2, (float4*)Q);

    k_pool_fc<<<B_, 256, 0, stream>>>(Q, batch, Wfc, bfc, out);
}

// Round 14
// 343.426 us; speedup vs baseline: 1.1424x; 1.0074x over previous
//
#include <hip/hip_runtime.h>

#define N_ 200000
#define E_ 6400000
#define F_ 128
#define H_ 16
#define C_ 10
#define B_ 512

#define CSH   14                     // src chunk: 16384 rows = 1 MB of P (L2-resident)
#define NCH   13                     // ceil(200000/16384)
#define SBSH  12                     // dst superbucket: 4096 nodes
#define NSB   49                     // ceil(200000/4096)
#define NKEY  (NCH * NSB)            // 637
#define NT    256                    // partition tiles (1 WG/CU; chunk = 25000/637 ~= 39 edges ~= 157 B >= 2 lines)
#define EPT   25000                  // NT*EPT == E_
#define N1    (N_ + 1)
#define STG2  11520                  // part2 staging cap (partition mean 10047, sigma ~100)
#define AGGB  1563                   // ceil(N_*2/256): 2 nodes per thread

// ---------- 1. count1: per-tile histogram over (chunk, sb) keys, direct from row/col ----------
__global__ __launch_bounds__(256) void k_count1(const int* __restrict__ row, const int* __restrict__ col,
                                                int* __restrict__ cnt1) {
    __shared__ int hist[NKEY];
    int tid = threadIdx.x, tile = blockIdx.x;
    for (int i = tid; i < NKEY; i += 256) hist[i] = 0;
    __syncthreads();
    const int* r = row + (size_t)tile * EPT;
    const int* c = col + (size_t)tile * EPT;
    for (int i = tid; i < EPT; i += 256) {
        int key = (r[i] >> CSH) * NSB + (c[i] >> SBSH);
        atomicAdd(&hist[key], 1);
    }
    __syncthreads();
    for (int i = tid; i < NKEY; i += 256) cnt1[(size_t)i * NT + tile] = hist[i];   // key-major
}

// ---------- generic: per-key scan over NT tiles (4/thread), in place + totals ----------
__global__ __launch_bounds__(256) void k_scan_col(int* __restrict__ cnt_mat, int* __restrict__ keyTotal) {
    __shared__ int s[256];
    int k = blockIdx.x, t = threadIdx.x;
    int v[4];
    int seg = 0;
#pragma unroll
    for (int j = 0; j < 4; ++j) {
        int idx = 4 * t + j;
        v[j] = (idx < NT) ? cnt_mat[(size_t)k * NT + idx] : 0;
        seg += v[j];
    }
    s[t] = seg;
    __syncthreads();
    for (int off = 1; off < 256; off <<= 1) {
        int tmp = (t >= off) ? s[t - off] : 0;
        __syncthreads();
        s[t] += tmp;
        __syncthreads();
    }
    if (t == 255) keyTotal[k] = s[255];
    int running = s[t] - seg;
#pragma unroll
    for (int j = 0; j < 4; ++j) {
        int idx = 4 * t + j;
        if (idx < NT) {
            int old = v[j];
            cnt_mat[(size_t)k * NT + idx] = running;
            running += old;
        }
    }
}

// ---------- generic: scan n totals (n<=1024) -> start[n+1] ----------
__global__ __launch_bounds__(1024) void k_scan_top(const int* __restrict__ keyTotal, int* __restrict__ keyStart, int n) {
    __shared__ int s[1024];
    int t = threadIdx.x;
    int v = (t < n) ? keyTotal[t] : 0;
    s[t] = v;
    __syncthreads();
    for (int off = 1; off < 1024; off <<= 1) {
        int tmp = (t >= off) ? s[t - off] : 0;
        __syncthreads();
        s[t] += tmp;
        __syncthreads();
    }
    if (t < n) keyStart[t] = s[t] - v;
    if (t == n - 1) keyStart[n] = s[t];
}

// ---------- 2. part1: single-stage scatter by (chunk, sb); word = dstlocal<<14 | srcL ----------
__global__ __launch_bounds__(256) void k_part1(const int* __restrict__ row, const int* __restrict__ col,
                                               const int* __restrict__ cnt1, const int* __restrict__ ks1,
                                               unsigned int* __restrict__ edges1) {
    __shared__ int cur[NKEY];
    int tid = threadIdx.x, tile = blockIdx.x;
    for (int i = tid; i < NKEY; i += 256) cur[i] = cnt1[(size_t)i * NT + tile] + ks1[i];
    __syncthreads();
    const int* r = row + (size_t)tile * EPT;
    const int* c = col + (size_t)tile * EPT;
    for (int i = tid; i < EPT; i += 256) {
        int src = r[i], dst = c[i];
        int key = (src >> CSH) * NSB + (dst >> SBSH);
        int p = atomicAdd(&cur[key], 1);
        edges1[p] = ((unsigned int)(dst & 4095) << CSH) | (unsigned int)(src & 16383);
    }
}

// ---------- 3. part2: per-(c,sb) 12-bit LDS counting sort by dst; writes off16 (+sentinel), final src ----------
__global__ __launch_bounds__(256) void k_part2(unsigned int* __restrict__ edges1, const int* __restrict__ ks1,
                                               unsigned short* __restrict__ off16, unsigned int* __restrict__ spill) {
    __shared__ unsigned int stg[STG2];   // 45 KB
    __shared__ int cnt[4096];            // 16 KB
    __shared__ int aux[256];             // 1 KB
    int b = blockIdx.x, tid = threadIdx.x;
    int c = b / NSB, sb = b % NSB;
    int s = ks1[b], e = ks1[b + 1], len = e - s;
    // fused sentinel: total length of the last superbucket's partition
    if (sb == NSB - 1 && tid == 0) off16[(size_t)c * N1 + N_] = (unsigned short)len;
    for (int i = tid; i < 4096; i += 256) cnt[i] = 0;
    __syncthreads();
    bool small = (len <= STG2);
    if (small) {
        for (int i = tid; i < len; i += 256) {
            unsigned int w = edges1[s + i];
            stg[i] = w;
            atomicAdd(&cnt[w >> CSH], 1);
        }
    } else {   // statistically unreachable; correct fallback via spill (P/Q region, dead here)
        for (int i = tid; i < len; i += 256) {
            unsigned int w = edges1[s + i];
            spill[s + i] = w;
            atomicAdd(&cnt[w >> CSH], 1);
        }
    }
    __syncthreads();
    // exclusive scan of cnt[4096]: 16 per thread + block scan
    int base = tid * 16;
    int vals[16];
    int run = 0;
#pragma unroll
    for (int j = 0; j < 16; ++j) { vals[j] = cnt[base + j]; run += vals[j]; }
    aux[tid] = run;
    __syncthreads();
    for (int o = 1; o < 256; o <<= 1) {
        int tmp = (tid >= o) ? aux[tid - o] : 0;
        __syncthreads();
        aux[tid] += tmp;
        __syncthreads();
    }
    int acc = aux[tid] - run;              // exclusive base for this thread's 16 keys
    int nb = (sb << SBSH) + base;
#pragma unroll
    for (int j = 0; j < 16; ++j) {
        int v = vals[j];
        cnt[base + j] = acc;               // becomes running cursor
        int n = nb + j;
        if (n < N_) off16[(size_t)c * N1 + n] = (unsigned short)acc;
        acc += v;
    }
    __syncthreads();
    if (small) {
        for (int i = tid; i < len; i += 256) {
            unsigned int w = stg[i];
            int pos = atomicAdd(&cnt[w >> CSH], 1);
            edges1[s + pos] = ((unsigned int)c << CSH) | (w & 16383u);
        }
    } else {
        for (int i = tid; i < len; i += 256) {
            unsigned int w = spill[s + i];
            int pos = atomicAdd(&cnt[w >> CSH], 1);
            edges1[s + pos] = ((unsigned int)c << CSH) | (w & 16383u);
        }
    }
}

// ---------- 4. GEMM1 (+fused dis): dis[n]=rsqrt(1+deg from off16); P = dis*(x@W1) ----------
__global__ __launch_bounds__(256) void k_gemm1s(const float* __restrict__ x, const float* __restrict__ W1,
                                                const unsigned short* __restrict__ off16, const int* __restrict__ ks1g,
                                                float* __restrict__ dis, float* __restrict__ P) {
    __shared__ float w[F_ * H_];
    __shared__ int ks[NKEY + 1];
    for (int i = threadIdx.x; i < F_ * H_; i += 256) w[i] = W1[i];
    for (int i = threadIdx.x; i <= NKEY; i += 256) ks[i] = ks1g[i];
    __syncthreads();
    int n = blockIdx.x * 256 + threadIdx.x;
    if (n >= N_) return;
    int sb = n >> SBSH, sb1 = (n + 1) >> SBSH;
    int deg = 0;
#pragma unroll
    for (int c = 0; c < NCH; ++c) {
        int s = ks[c * NSB + sb]  + off16[(size_t)c * N1 + n];
        int e = ks[c * NSB + sb1] + off16[(size_t)c * N1 + n + 1];
        deg += e - s;
    }
    float dn = rsqrtf(1.0f + (float)deg);
    dis[n] = dn;
    float acc[H_];
#pragma unroll
    for (int h = 0; h < H_; ++h) acc[h] = 0.f;
    const float4* xr = reinterpret_cast<const float4*>(x + (size_t)n * F_);
#pragma unroll 4
    for (int k4 = 0; k4 < F_ / 4; ++k4) {
        float4 xv = xr[k4];
        int k = k4 * 4;
#pragma unroll
        for (int h = 0; h < H_; ++h) {
            acc[h] += xv.x * w[(k + 0) * H_ + h] + xv.y * w[(k + 1) * H_ + h]
                    + xv.z * w[(k + 2) * H_ + h] + xv.w * w[(k + 3) * H_ + h];
        }
    }
    float* o = P + (size_t)n * H_;
#pragma unroll
    for (int h = 0; h < H_; h += 4)
        *(float4*)(o + h) = make_float4(acc[h] * dn, acc[h + 1] * dn, acc[h + 2] * dn, acc[h + 3] * dn);
}

// ---------- 6. GEMM2: P = dis*(hin@W2)  (hin already ReLU'd by agg<1>) ----------
__global__ __launch_bounds__(256) void k_gemm2s(const float* __restrict__ hin, const float* __restrict__ W2,
                                                const float* __restrict__ dis, float* __restrict__ P) {
    __shared__ float w[H_ * H_];
    if (threadIdx.x < H_ * H_) w[threadIdx.x] = W2[threadIdx.x];
    __syncthreads();
    int n = blockIdx.x * 256 + threadIdx.x;
    if (n >= N_) return;
    float hv[H_];
    const float4* hr = reinterpret_cast<const float4*>(hin + (size_t)n * H_);
#pragma unroll
    for (int q = 0; q < 4; ++q) {
        float4 v = hr[q];
        hv[q * 4 + 0] = v.x; hv[q * 4 + 1] = v.y; hv[q * 4 + 2] = v.z; hv[q * 4 + 3] = v.w;
    }
    float acc[H_];
#pragma unroll
    for (int h = 0; h < H_; ++h) acc[h] = 0.f;
#pragma unroll
    for (int k = 0; k < H_; ++k)
#pragma unroll
        for (int h = 0; h < H_; ++h) acc[h] += hv[k] * w[k * H_ + h];
    float dn = dis[n];
    float* o = P + (size_t)n * H_;
#pragma unroll
    for (int h = 0; h < H_; h += 4)
        *(float4*)(o + h) = make_float4(acc[h] * dn, acc[h + 1] * dn, acc[h + 2] * dn, acc[h + 3] * dn);
}

// ---------- 5/7. CSR aggregation: 2 adjacent nodes per thread, flat per-chunk range ----------
// thread = (node-pair, hq); within partition (c,sb) the pair's sublists are contiguous ->
// one flat loop [s0,e1) with independent iterations; membership = 1 compare.
// Invariants: wave walks one chunk window at a time in order; 4 hq-lanes per 64B line.
template <int RELU>
__global__ __launch_bounds__(256) void k_agg(const float4* __restrict__ P4, const unsigned int* __restrict__ csr,
                                             const unsigned short* __restrict__ off16, const int* __restrict__ ks1g,
                                             const float* __restrict__ dis, const float* __restrict__ bias,
                                             float4* __restrict__ Q4) {
    __shared__ int ks[NKEY + 1];
    for (int i = threadIdx.x; i <= NKEY; i += 256) ks[i] = ks1g[i];
    __syncthreads();
    int g = threadIdx.x >> 2, hq = threadIdx.x & 3;
    int n0 = blockIdx.x * 128 + g * 2;             // node pair n0, n0+1 (N_ even)
    if (n0 >= N_) return;
    int sb  = n0 >> SBSH;                          // pair never straddles sb (2 | 4096)
    int sbE = (n0 + 2) >> SBSH;                    // for the pair-end bound
    float4 acc0 = {0,0,0,0}, acc1 = {0,0,0,0};
    // pipelined bounds: chunk-0 offsets (n0 even -> ushort2 aligned)
    const unsigned short* ob = off16 + n0;
    ushort2 o2 = *(const ushort2*)ob;
    unsigned short oE = ob[2];
#pragma unroll
    for (int c = 0; c < NCH; ++c) {
        int bs = ks[c * NSB + sb];
        int be = ks[c * NSB + sbE];
        int s0 = bs + o2.x;
        int s1 = bs + o2.y;
        int e1 = be + oE;
        if (c + 1 < NCH) {                         // prefetch next chunk's offsets
            const unsigned short* obn = off16 + (size_t)(c + 1) * N1 + n0;
            o2 = *(const ushort2*)obn;
            oE = obn[2];
        }
#pragma unroll 4
        for (int p = s0; p < e1; ++p) {
            float4 v = P4[(size_t)csr[p] * 4 + hq];
            float w0 = (p < s1) ? 1.f : 0.f;
            float w1 = 1.f - w0;
            acc0.x += w0 * v.x; acc0.y += w0 * v.y; acc0.z += w0 * v.z; acc0.w += w0 * v.w;
            acc1.x += w1 * v.x; acc1.y += w1 * v.y; acc1.z += w1 * v.z; acc1.w += w1 * v.w;
        }
    }
    float2 d2 = *(const float2*)(dis + n0);
    float4 b4 = ((const float4*)bias)[hq];
#define FINISH(ACC, K, DN)                                            \
    {                                                                 \
        float4 self = P4[(size_t)(n0 + K) * 4 + hq];                  \
        float4 v;                                                     \
        v.x = (DN) * (ACC.x + self.x) + b4.x;                         \
        v.y = (DN) * (ACC.y + self.y) + b4.y;                         \
        v.z = (DN) * (ACC.z + self.z) + b4.z;                         \
        v.w = (DN) * (ACC.w + self.w) + b4.w;                         \
        if (RELU) {                                                   \
            v.x = fmaxf(v.x, 0.f); v.y = fmaxf(v.y, 0.f);             \
            v.z = fmaxf(v.z, 0.f); v.w = fmaxf(v.w, 0.f);             \
        }                                                             \
        Q4[(size_t)(n0 + K) * 4 + hq] = v;                            \
    }
    FINISH(acc0, 0, d2.x)
    FINISH(acc1, 1, d2.y)
#undef FINISH
}

// ---------- 8. pool + fc ----------
__global__ __launch_bounds__(256) void k_pool_fc(const float* __restrict__ h2, const int* __restrict__ batch,
                                                 const float* __restrict__ Wfc, const float* __restrict__ bfc,
                                                 float* __restrict__ out) {
    int b = blockIdx.x;
    int lo = 0, hi = N_;
    while (lo < hi) { int m = (lo + hi) >> 1; if (batch[m] < b) lo = m + 1; else hi = m; }
    int start = lo;
    lo = start; hi = N_;
    while (lo < hi) { int m = (lo + hi) >> 1; if (batch[m] < b + 1) lo = m + 1; else hi = m; }
    int end = lo;

    int t = threadIdx.x;
    int h = t & 15, q = t >> 4;
    float acc = 0.f;
    for (int n = start + q; n < end; n += 16) acc += h2[(size_t)n * H_ + h];
    acc += __shfl_xor(acc, 16);
    acc += __shfl_xor(acc, 32);

    __shared__ float part[4][H_];
    __shared__ float pooled[H_];
    if ((t & 63) < 16) part[t >> 6][h] = acc;
    __syncthreads();
    if (t < H_) {
        float s2 = part[0][t] + part[1][t] + part[2][t] + part[3][t];
        pooled[t] = s2 / fmaxf((float)(end - start), 1.0f);
    }
    __syncthreads();
    if (t < C_) {
        float o = bfc[t];
#pragma unroll
        for (int hh = 0; hh < H_; ++hh) o += pooled[hh] * Wfc[hh * C_ + t];
        out[b * C_ + t] = o;
    }
}

extern "C" void kernel_launch(void* const* d_in, const int* in_sizes, int n_in,
                              void* d_out, int out_size, void* d_ws, size_t ws_size,
                              hipStream_t stream) {
    const float* x    = (const float*)d_in[0];
    const int*   ei   = (const int*)d_in[1];
    const int*   batch= (const int*)d_in[2];
    const float* W1   = (const float*)d_in[3];
    const float* b1   = (const float*)d_in[4];
    const float* W2   = (const float*)d_in[5];
    const float* b2   = (const float*)d_in[6];
    const float* Wfc  = (const float*)d_in[7];
    const float* bfc  = (const float*)d_in[8];
    float* out = (float*)d_out;

    const int* row = ei;          // sources
    const int* col = ei + E_;     // destinations

    size_t off = 0;
    auto alloc = [&](size_t bytes) -> void* {
        void* p = (char*)d_ws + off;
        off += (bytes + 255) & ~(size_t)255;
        return p;
    };
    // union: cnt1 (637*256*4 = 652 KB) dead after k_part1; off16 (13*N1*2 = 5.2 MB) written in k_part2
    char*           U        = (char*)alloc((size_t)NCH * N1 * 2);
    int*            cnt1     = (int*)U;
    unsigned short* off16    = (unsigned short*)U;
    int*            keyTotal = (int*)alloc((size_t)NKEY * 4);
    int*            ks1      = (int*)alloc((size_t)(NKEY + 1) * 4);
    unsigned int*   edges1   = (unsigned int*)alloc((size_t)E_ * 4);     // 25.6 MB
    float*          dis      = (float*)alloc((size_t)N_ * 4);            // 0.8 MB
    float*          P        = (float*)alloc((size_t)N_ * H_ * 4);       // 12.8 MB
    float*          Q        = (float*)alloc((size_t)N_ * H_ * 4);       // 12.8 MB, contiguous after P
    unsigned int*   spill    = (unsigned int*)P;                         // part2 fallback; P/Q dead until gemm1
    (void)ws_size; (void)in_sizes; (void)n_in; (void)out_size;

    const int gridN = (N_ + 255) / 256;

    // single-stage partition by (chunk, dst>>12) directly from row/col
    k_count1  <<<NT, 256, 0, stream>>>(row, col, cnt1);
    k_scan_col<<<NKEY, 256, 0, stream>>>(cnt1, keyTotal);
    k_scan_top<<<1, 1024, 0, stream>>>(keyTotal, ks1, NKEY);
    k_part1   <<<NT, 256, 0, stream>>>(row, col, cnt1, ks1, edges1);
    // in-partition 12-bit sort by dst -> per-chunk CSR (off16 + sentinel) + final src edges
    k_part2   <<<NKEY, 256, 0, stream>>>(edges1, ks1, off16, spill);

    // conv1 (dis fused into gemm1)
    k_gemm1s<<<gridN, 256, 0, stream>>>(x, W1, off16, ks1, dis, P);
    k_agg<1><<<AGGB, 256, 0, stream>>>((const float4*)P, edges1, off16, ks1, dis, b1, (float4*)Q);
    // conv2
    k_gemm2s<<<gridN, 256, 0, stream>>>(Q, W2, dis, P);
    k_agg<0><<<AGGB, 256, 0, stream>>>((const float4*)P, edges1, off16, ks1, dis, b2, (float4*)Q);

    k_pool_fc<<<B_, 256, 0, stream>>>(Q, batch, Wfc, bfc, out);
}

// Round 15
// 300.668 us; speedup vs baseline: 1.3048x; 1.1422x over previous
//
#include <hip/hip_runtime.h>

#define N_ 200000
#define E_ 6400000
#define F_ 128
#define H_ 16
#define C_ 10
#define B_ 512

#define CSH   15                     // src chunk: 32768 rows = 2 MB of P (L2-resident window)
#define NCH   7                      // ceil(200000/32768)
#define SBSH  11                     // dst superbucket: 2048 nodes
#define NSB   98                     // ceil(200000/2048)
#define NKEY  (NCH * NSB)            // 686
#define NT    256                    // partition tiles (chunk = 25000/686 ~= 36 edges ~= 146 B >= 2 lines)
#define EPT   25000                  // NT*EPT == E_
#define N1    (N_ + 1)
#define STG2  11520                  // part2 staging cap (partition mean 9329, sigma ~97)
#define AGGB  1563                   // ceil(N_*2/256): 2 nodes per thread

// ---------- 1. count1: per-tile histogram over (chunk, sb) keys, 1024-thread blocks ----------
__global__ __launch_bounds__(1024) void k_count1(const int* __restrict__ row, const int* __restrict__ col,
                                                 int* __restrict__ cnt1) {
    __shared__ int hist[NKEY];
    int tid = threadIdx.x, tile = blockIdx.x;
    for (int i = tid; i < NKEY; i += 1024) hist[i] = 0;
    __syncthreads();
    const int* r = row + (size_t)tile * EPT;
    const int* c = col + (size_t)tile * EPT;
    for (int i = tid; i < EPT; i += 1024) {
        int key = (r[i] >> CSH) * NSB + (c[i] >> SBSH);
        atomicAdd(&hist[key], 1);
    }
    __syncthreads();
    for (int i = tid; i < NKEY; i += 1024) cnt1[(size_t)i * NT + tile] = hist[i];   // key-major
}

// ---------- generic: per-key scan over NT tiles (4/thread), in place + totals ----------
__global__ __launch_bounds__(256) void k_scan_col(int* __restrict__ cnt_mat, int* __restrict__ keyTotal) {
    __shared__ int s[256];
    int k = blockIdx.x, t = threadIdx.x;
    int v[4];
    int seg = 0;
#pragma unroll
    for (int j = 0; j < 4; ++j) {
        int idx = 4 * t + j;
        v[j] = (idx < NT) ? cnt_mat[(size_t)k * NT + idx] : 0;
        seg += v[j];
    }
    s[t] = seg;
    __syncthreads();
    for (int off = 1; off < 256; off <<= 1) {
        int tmp = (t >= off) ? s[t - off] : 0;
        __syncthreads();
        s[t] += tmp;
        __syncthreads();
    }
    if (t == 255) keyTotal[k] = s[255];
    int running = s[t] - seg;
#pragma unroll
    for (int j = 0; j < 4; ++j) {
        int idx = 4 * t + j;
        if (idx < NT) {
            int old = v[j];
            cnt_mat[(size_t)k * NT + idx] = running;
            running += old;
        }
    }
}

// ---------- generic: scan n totals (n<=1024) -> start[n+1] ----------
__global__ __launch_bounds__(1024) void k_scan_top(const int* __restrict__ keyTotal, int* __restrict__ keyStart, int n) {
    __shared__ int s[1024];
    int t = threadIdx.x;
    int v = (t < n) ? keyTotal[t] : 0;
    s[t] = v;
    __syncthreads();
    for (int off = 1; off < 1024; off <<= 1) {
        int tmp = (t >= off) ? s[t - off] : 0;
        __syncthreads();
        s[t] += tmp;
        __syncthreads();
    }
    if (t < n) keyStart[t] = s[t] - v;
    if (t == n - 1) keyStart[n] = s[t];
}

// ---------- 2. part1: scatter by (chunk, sb); word = dstlocal<<15 | srcL; 1024-thread blocks ----------
__global__ __launch_bounds__(1024) void k_part1(const int* __restrict__ row, const int* __restrict__ col,
                                                const int* __restrict__ cnt1, const int* __restrict__ ks1,
                                                unsigned int* __restrict__ edges1) {
    __shared__ int cur[NKEY];
    int tid = threadIdx.x, tile = blockIdx.x;
    for (int i = tid; i < NKEY; i += 1024) cur[i] = cnt1[(size_t)i * NT + tile] + ks1[i];
    __syncthreads();
    const int* r = row + (size_t)tile * EPT;
    const int* c = col + (size_t)tile * EPT;
    for (int i = tid; i < EPT; i += 1024) {
        int src = r[i], dst = c[i];
        int key = (src >> CSH) * NSB + (dst >> SBSH);
        int p = atomicAdd(&cur[key], 1);
        edges1[p] = ((unsigned int)(dst & 2047) << CSH) | (unsigned int)(src & 32767);
    }
}

// ---------- 3. part2: per-(c,sb) 11-bit LDS counting sort by dst; writes off16 (+sentinel), final src ----------
__global__ __launch_bounds__(256) void k_part2(unsigned int* __restrict__ edges1, const int* __restrict__ ks1,
                                               unsigned short* __restrict__ off16, unsigned int* __restrict__ spill) {
    __shared__ unsigned int stg[STG2];   // 45 KB
    __shared__ int cnt[2048];            // 8 KB
    __shared__ int aux[256];             // 1 KB
    int b = blockIdx.x, tid = threadIdx.x;
    int c = b / NSB, sb = b % NSB;
    int s = ks1[b], e = ks1[b + 1], len = e - s;
    // fused sentinel: total length of the last superbucket's partition
    if (sb == NSB - 1 && tid == 0) off16[(size_t)c * N1 + N_] = (unsigned short)len;
    for (int i = tid; i < 2048; i += 256) cnt[i] = 0;
    __syncthreads();
    bool small = (len <= STG2);
    if (small) {
        for (int i = tid; i < len; i += 256) {
            unsigned int w = edges1[s + i];
            stg[i] = w;
            atomicAdd(&cnt[w >> CSH], 1);
        }
    } else {   // statistically unreachable (cap = mean+22sigma); correct fallback via spill
        for (int i = tid; i < len; i += 256) {
            unsigned int w = edges1[s + i];
            spill[s + i] = w;
            atomicAdd(&cnt[w >> CSH], 1);
        }
    }
    __syncthreads();
    // exclusive scan of cnt[2048]: 8 per thread + block scan
    int base = tid * 8;
    int vals[8];
    int run = 0;
#pragma unroll
    for (int j = 0; j < 8; ++j) { vals[j] = cnt[base + j]; run += vals[j]; }
    aux[tid] = run;
    __syncthreads();
    for (int o = 1; o < 256; o <<= 1) {
        int tmp = (tid >= o) ? aux[tid - o] : 0;
        __syncthreads();
        aux[tid] += tmp;
        __syncthreads();
    }
    int acc = aux[tid] - run;              // exclusive base for this thread's 8 keys
    int nb = (sb << SBSH) + base;
#pragma unroll
    for (int j = 0; j < 8; ++j) {
        int v = vals[j];
        cnt[base + j] = acc;               // becomes running cursor
        int n = nb + j;
        if (n < N_) off16[(size_t)c * N1 + n] = (unsigned short)acc;
        acc += v;
    }
    __syncthreads();
    if (small) {
        for (int i = tid; i < len; i += 256) {
            unsigned int w = stg[i];
            int pos = atomicAdd(&cnt[w >> CSH], 1);
            edges1[s + pos] = ((unsigned int)c << CSH) | (w & 32767u);
        }
    } else {
        for (int i = tid; i < len; i += 256) {
            unsigned int w = spill[s + i];
            int pos = atomicAdd(&cnt[w >> CSH], 1);
            edges1[s + pos] = ((unsigned int)c << CSH) | (w & 32767u);
        }
    }
}

// ---------- 4. GEMM1 (+fused dis): dis[n]=rsqrt(1+deg from off16); P = dis*(x@W1) ----------
__global__ __launch_bounds__(256) void k_gemm1s(const float* __restrict__ x, const float* __restrict__ W1,
                                                const unsigned short* __restrict__ off16, const int* __restrict__ ks1g,
                                                float* __restrict__ dis, float* __restrict__ P) {
    __shared__ float w[F_ * H_];
    __shared__ int ks[NKEY + 1];
    for (int i = threadIdx.x; i < F_ * H_; i += 256) w[i] = W1[i];
    for (int i = threadIdx.x; i <= NKEY; i += 256) ks[i] = ks1g[i];
    __syncthreads();
    int n = blockIdx.x * 256 + threadIdx.x;
    if (n >= N_) return;
    int sb = n >> SBSH, sb1 = (n + 1) >> SBSH;
    int deg = 0;
#pragma unroll
    for (int c = 0; c < NCH; ++c) {
        int s = ks[c * NSB + sb]  + off16[(size_t)c * N1 + n];
        int e = ks[c * NSB + sb1] + off16[(size_t)c * N1 + n + 1];
        deg += e - s;
    }
    float dn = rsqrtf(1.0f + (float)deg);
    dis[n] = dn;
    float acc[H_];
#pragma unroll
    for (int h = 0; h < H_; ++h) acc[h] = 0.f;
    const float4* xr = reinterpret_cast<const float4*>(x + (size_t)n * F_);
#pragma unroll 4
    for (int k4 = 0; k4 < F_ / 4; ++k4) {
        float4 xv = xr[k4];
        int k = k4 * 4;
#pragma unroll
        for (int h = 0; h < H_; ++h) {
            acc[h] += xv.x * w[(k + 0) * H_ + h] + xv.y * w[(k + 1) * H_ + h]
                    + xv.z * w[(k + 2) * H_ + h] + xv.w * w[(k + 3) * H_ + h];
        }
    }
    float* o = P + (size_t)n * H_;
#pragma unroll
    for (int h = 0; h < H_; h += 4)
        *(float4*)(o + h) = make_float4(acc[h] * dn, acc[h + 1] * dn, acc[h + 2] * dn, acc[h + 3] * dn);
}

// ---------- 6. GEMM2: P = dis*(hin@W2)  (hin already ReLU'd by agg<1>) ----------
__global__ __launch_bounds__(256) void k_gemm2s(const float* __restrict__ hin, const float* __restrict__ W2,
                                                const float* __restrict__ dis, float* __restrict__ P) {
    __shared__ float w[H_ * H_];
    if (threadIdx.x < H_ * H_) w[threadIdx.x] = W2[threadIdx.x];
    __syncthreads();
    int n = blockIdx.x * 256 + threadIdx.x;
    if (n >= N_) return;
    float hv[H_];
    const float4* hr = reinterpret_cast<const float4*>(hin + (size_t)n * H_);
#pragma unroll
    for (int q = 0; q < 4; ++q) {
        float4 v = hr[q];
        hv[q * 4 + 0] = v.x; hv[q * 4 + 1] = v.y; hv[q * 4 + 2] = v.z; hv[q * 4 + 3] = v.w;
    }
    float acc[H_];
#pragma unroll
    for (int h = 0; h < H_; ++h) acc[h] = 0.f;
#pragma unroll
    for (int k = 0; k < H_; ++k)
#pragma unroll
        for (int h = 0; h < H_; ++h) acc[h] += hv[k] * w[k * H_ + h];
    float dn = dis[n];
    float* o = P + (size_t)n * H_;
#pragma unroll
    for (int h = 0; h < H_; h += 4)
        *(float4*)(o + h) = make_float4(acc[h] * dn, acc[h + 1] * dn, acc[h + 2] * dn, acc[h + 3] * dn);
}

// ---------- 5/7. CSR aggregation: 2 adjacent nodes per thread, flat per-chunk range ----------
// thread = (node-pair, hq); within partition (c,sb) the pair's sublists are contiguous ->
// one flat loop [s0,e1) with independent iterations; membership = 1 compare.
// Invariants: wave walks one chunk window at a time in order; 4 hq-lanes per 64B line.
template <int RELU>
__global__ __launch_bounds__(256) void k_agg(const float4* __restrict__ P4, const unsigned int* __restrict__ csr,
                                             const unsigned short* __restrict__ off16, const int* __restrict__ ks1g,
                                             const float* __restrict__ dis, const float* __restrict__ bias,
                                             float4* __restrict__ Q4) {
    __shared__ int ks[NKEY + 1];
    for (int i = threadIdx.x; i <= NKEY; i += 256) ks[i] = ks1g[i];
    __syncthreads();
    int g = threadIdx.x >> 2, hq = threadIdx.x & 3;
    int n0 = blockIdx.x * 128 + g * 2;             // node pair n0, n0+1 (N_ even)
    if (n0 >= N_) return;
    int sb  = n0 >> SBSH;                          // pair never straddles sb (2 | 2048)
    int sbE = (n0 + 2) >> SBSH;                    // for the pair-end bound
    float4 acc0 = {0,0,0,0}, acc1 = {0,0,0,0};
    // pipelined bounds: chunk-0 offsets (n0 even -> ushort2 aligned)
    const unsigned short* ob = off16 + n0;
    ushort2 o2 = *(const ushort2*)ob;
    unsigned short oE = ob[2];
#pragma unroll
    for (int c = 0; c < NCH; ++c) {
        int bs = ks[c * NSB + sb];
        int be = ks[c * NSB + sbE];
        int s0 = bs + o2.x;
        int s1 = bs + o2.y;
        int e1 = be + oE;
        if (c + 1 < NCH) {                         // prefetch next chunk's offsets
            const unsigned short* obn = off16 + (size_t)(c + 1) * N1 + n0;
            o2 = *(const ushort2*)obn;
            oE = obn[2];
        }
#pragma unroll 4
        for (int p = s0; p < e1; ++p) {
            float4 v = P4[(size_t)csr[p] * 4 + hq];
            float w0 = (p < s1) ? 1.f : 0.f;
            float w1 = 1.f - w0;
            acc0.x += w0 * v.x; acc0.y += w0 * v.y; acc0.z += w0 * v.z; acc0.w += w0 * v.w;
            acc1.x += w1 * v.x; acc1.y += w1 * v.y; acc1.z += w1 * v.z; acc1.w += w1 * v.w;
        }
    }
    float2 d2 = *(const float2*)(dis + n0);
    float4 b4 = ((const float4*)bias)[hq];
#define FINISH(ACC, K, DN)                                            \
    {                                                                 \
        float4 self = P4[(size_t)(n0 + K) * 4 + hq];                  \
        float4 v;                                                     \
        v.x = (DN) * (ACC.x + self.x) + b4.x;                         \
        v.y = (DN) * (ACC.y + self.y) + b4.y;                         \
        v.z = (DN) * (ACC.z + self.z) + b4.z;                         \
        v.w = (DN) * (ACC.w + self.w) + b4.w;                         \
        if (RELU) {                                                   \
            v.x = fmaxf(v.x, 0.f); v.y = fmaxf(v.y, 0.f);             \
            v.z = fmaxf(v.z, 0.f); v.w = fmaxf(v.w, 0.f);             \
        }                                                             \
        Q4[(size_t)(n0 + K) * 4 + hq] = v;                            \
    }
    FINISH(acc0, 0, d2.x)
    FINISH(acc1, 1, d2.y)
#undef FINISH
}

// ---------- 8. pool + fc ----------
__global__ __launch_bounds__(256) void k_pool_fc(const float* __restrict__ h2, const int* __restrict__ batch,
                                                 const float* __restrict__ Wfc, const float* __restrict__ bfc,
                                                 float* __restrict__ out) {
    int b = blockIdx.x;
    int lo = 0, hi = N_;
    while (lo < hi) { int m = (lo + hi) >> 1; if (batch[m] < b) lo = m + 1; else hi = m; }
    int start = lo;
    lo = start; hi = N_;
    while (lo < hi) { int m = (lo + hi) >> 1; if (batch[m] < b + 1) lo = m + 1; else hi = m; }
    int end = lo;

    int t = threadIdx.x;
    int h = t & 15, q = t >> 4;
    float acc = 0.f;
    for (int n = start + q; n < end; n += 16) acc += h2[(size_t)n * H_ + h];
    acc += __shfl_xor(acc, 16);
    acc += __shfl_xor(acc, 32);

    __shared__ float part[4][H_];
    __shared__ float pooled[H_];
    if ((t & 63) < 16) part[t >> 6][h] = acc;
    __syncthreads();
    if (t < H_) {
        float s2 = part[0][t] + part[1][t] + part[2][t] + part[3][t];
        pooled[t] = s2 / fmaxf((float)(end - start), 1.0f);
    }
    __syncthreads();
    if (t < C_) {
        float o = bfc[t];
#pragma unroll
        for (int hh = 0; hh < H_; ++hh) o += pooled[hh] * Wfc[hh * C_ + t];
        out[b * C_ + t] = o;
    }
}

extern "C" void kernel_launch(void* const* d_in, const int* in_sizes, int n_in,
                              void* d_out, int out_size, void* d_ws, size_t ws_size,
                              hipStream_t stream) {
    const float* x    = (const float*)d_in[0];
    const int*   ei   = (const int*)d_in[1];
    const int*   batch= (const int*)d_in[2];
    const float* W1   = (const float*)d_in[3];
    const float* b1   = (const float*)d_in[4];
    const float* W2   = (const float*)d_in[5];
    const float* b2   = (const float*)d_in[6];
    const float* Wfc  = (const float*)d_in[7];
    const float* bfc  = (const float*)d_in[8];
    float* out = (float*)d_out;

    const int* row = ei;          // sources
    const int* col = ei + E_;     // destinations

    size_t off = 0;
    auto alloc = [&](size_t bytes) -> void* {
        void* p = (char*)d_ws + off;
        off += (bytes + 255) & ~(size_t)255;
        return p;
    };
    // union: cnt1 (686*256*4 = 702 KB) dead after k_part1; off16 (7*N1*2 = 2.8 MB) written in k_part2
    char*           U        = (char*)alloc((size_t)NCH * N1 * 2);
    int*            cnt1     = (int*)U;
    unsigned short* off16    = (unsigned short*)U;
    int*            keyTotal = (int*)alloc((size_t)NKEY * 4);
    int*            ks1      = (int*)alloc((size_t)(NKEY + 1) * 4);
    unsigned int*   edges1   = (unsigned int*)alloc((size_t)E_ * 4);     // 25.6 MB
    float*          dis      = (float*)alloc((size_t)N_ * 4);            // 0.8 MB
    float*          P        = (float*)alloc((size_t)N_ * H_ * 4);       // 12.8 MB
    float*          Q        = (float*)alloc((size_t)N_ * H_ * 4);       // 12.8 MB, contiguous after P
    unsigned int*   spill    = (unsigned int*)P;                         // part2 fallback; P/Q dead until gemm1
    (void)ws_size; (void)in_sizes; (void)n_in; (void)out_size;

    const int gridN = (N_ + 255) / 256;

    // single-stage partition by (chunk, dst>>11) directly from row/col (1024-thread blocks)
    k_count1  <<<NT, 1024, 0, stream>>>(row, col, cnt1);
    k_scan_col<<<NKEY, 256, 0, stream>>>(cnt1, keyTotal);
    k_scan_top<<<1, 1024, 0, stream>>>(keyTotal, ks1, NKEY);
    k_part1   <<<NT, 1024, 0, stream>>>(row, col, cnt1, ks1, edges1);
    // in-partition 11-bit sort by dst -> per-chunk CSR (off16 + sentinel) + final src edges
    k_part2   <<<NKEY, 256, 0, stream>>>(edges1, ks1, off16, spill);

    // conv1 (dis fused into gemm1)
    k_gemm1s<<<gridN, 256, 0, stream>>>(x, W1, off16, ks1, dis, P);
    k_agg<1><<<AGGB, 256, 0, stream>>>((const float4*)P, edges1, off16, ks1, dis, b1, (float4*)Q);
    // conv2
    k_gemm2s<<<gridN, 256, 0, stream>>>(Q, W2, dis, P);
    k_agg<0><<<AGGB, 256, 0, stream>>>((const float4*)P, edges1, off16, ks1, dis, b2, (float4*)Q);

    k_pool_fc<<<B_, 256, 0, stream>>>(Q, batch, Wfc, bfc, out);
}